// Round 4
// baseline (207.409 us; speedup 1.0000x reference)
//
#include <hip/hip_runtime.h>
#include <math.h>

#define DT 0.005f
#define NTHREADS 256

typedef float fvec4 __attribute__((ext_vector_type(4)));
typedef float fvec2 __attribute__((ext_vector_type(2)));
typedef int   ivec2 __attribute__((ext_vector_type(2)));

__global__ __launch_bounds__(NTHREADS) void pos_loss_fused(
    const float* __restrict__ quat,     // B*4
    const float* __restrict__ tpos,     // B*3
    const float* __restrict__ bias,     // B*3
    const float* __restrict__ batchX,   // B*S*F
    const float* __restrict__ pos_all,  // N*3
    const float* __restrict__ vel_all,  // N*3
    const float* __restrict__ grav,     // 3
    const int*   __restrict__ indices,  // B
    const int*   __restrict__ seq_len_p,// 1
    int B, int SF,
    float* __restrict__ partials,
    unsigned* __restrict__ counter,
    float inv_cnt,
    float* __restrict__ out,
    int nblocks)
{
    const int S = *seq_len_p;
    const int F = SF / S;
    const int last_off = (S - 1) * F;
    const float gx = grav[0], gy = grav[1], gz = grav[2];
    const float half_dt2 = 0.5f * DT * DT;

    float hsum = 0.f;
    const int nchunks = B >> 1;          // 2 elements per chunk
    const int stride = gridDim.x * blockDim.x;

    for (int c = blockIdx.x * blockDim.x + threadIdx.x; c < nchunks; c += stride) {
        const size_t i0 = (size_t)c * 2;

        // index load first, gathers issued immediately (longest dep chain)
        ivec2 iv = *reinterpret_cast<const ivec2*>(indices + i0);
        int ix0 = iv.x - (S - 1); if (ix0 < 0) ix0 = 0;
        int ix1 = iv.y - (S - 1); if (ix1 < 0) ix1 = 0;

        const float* pp0 = pos_all + (size_t)ix0 * 3;
        const float* vp0 = vel_all + (size_t)ix0 * 3;
        const float* pp1 = pos_all + (size_t)ix1 * 3;
        const float* vp1 = vel_all + (size_t)ix1 * 3;
        float p00 = pp0[0], p01 = pp0[1], p02 = pp0[2];
        float v00 = vp0[0], v01 = vp0[1], v02 = vp0[2];
        float p10 = pp1[0], p11 = pp1[1], p12 = pp1[2];
        float v10 = vp1[0], v11 = vp1[1], v12 = vp1[2];

        // streaming loads (all 8B/16B vectorized, aligned)
        fvec4 q0 = *reinterpret_cast<const fvec4*>(quat + i0 * 4);
        fvec4 q1 = *reinterpret_cast<const fvec4*>(quat + i0 * 4 + 4);

        fvec2 tpa = *reinterpret_cast<const fvec2*>(tpos + i0 * 3);
        fvec2 tpb = *reinterpret_cast<const fvec2*>(tpos + i0 * 3 + 2);
        fvec2 tpc = *reinterpret_cast<const fvec2*>(tpos + i0 * 3 + 4);

        fvec2 bpa = *reinterpret_cast<const fvec2*>(bias + i0 * 3);
        fvec2 bpb = *reinterpret_cast<const fvec2*>(bias + i0 * 3 + 2);
        fvec2 bpc = *reinterpret_cast<const fvec2*>(bias + i0 * 3 + 4);

        const float* xb0 = batchX + i0 * SF + last_off;
        const float* xb1 = batchX + (i0 + 1) * SF + last_off;
        float ax0 = xb0[0], ay0 = xb0[1], az0 = xb0[2];
        float ax1 = xb1[0], ay1 = xb1[1], az1 = xb1[2];

        // ---- element 0 ----
        {
            float qx = q0.x, qy = q0.y, qz = q0.z, qw = q0.w;
            float ax = ax0 - bpa.x, ay = ay0 - bpa.y, az = az0 - bpb.x;

            float t0 = -(qy * ax + qz * ay + qw * az);
            float t1 =   qx * ax + qz * az - qw * ay;
            float t2 =   qx * ay - qy * az + qw * ax;
            float t3 =   qx * az + qy * ay - qz * ax;
            float rx = -t0 * qy + t1 * qx - t2 * qw + t3 * qz;
            float ry = -t0 * qz + t1 * qw + t2 * qx - t3 * qy;
            float rz = -t0 * qw - t1 * qz + t2 * qy + t3 * qx;

            float px = p00 + v00 * DT + half_dt2 * gx + half_dt2 * rx;
            float py = p01 + v01 * DT + half_dt2 * gy + half_dt2 * ry;
            float pz = p02 + v02 * DT + half_dt2 * gz + half_dt2 * rz;

            float dx = px - tpa.x, dy = py - tpa.y, dz = pz - tpb.x;
            float adx = fabsf(dx), ady = fabsf(dy), adz = fabsf(dz);
            hsum += (adx < 1.f) ? 0.5f * dx * dx : adx - 0.5f;
            hsum += (ady < 1.f) ? 0.5f * dy * dy : ady - 0.5f;
            hsum += (adz < 1.f) ? 0.5f * dz * dz : adz - 0.5f;
        }
        // ---- element 1 ----
        {
            float qx = q1.x, qy = q1.y, qz = q1.z, qw = q1.w;
            float ax = ax1 - bpb.y, ay = ay1 - bpc.x, az = az1 - bpc.y;

            float t0 = -(qy * ax + qz * ay + qw * az);
            float t1 =   qx * ax + qz * az - qw * ay;
            float t2 =   qx * ay - qy * az + qw * ax;
            float t3 =   qx * az + qy * ay - qz * ax;
            float rx = -t0 * qy + t1 * qx - t2 * qw + t3 * qz;
            float ry = -t0 * qz + t1 * qw + t2 * qx - t3 * qy;
            float rz = -t0 * qw - t1 * qz + t2 * qy + t3 * qx;

            float px = p10 + v10 * DT + half_dt2 * gx + half_dt2 * rx;
            float py = p11 + v11 * DT + half_dt2 * gy + half_dt2 * ry;
            float pz = p12 + v12 * DT + half_dt2 * gz + half_dt2 * rz;

            float dx = px - tpb.y, dy = py - tpc.x, dz = pz - tpc.y;
            float adx = fabsf(dx), ady = fabsf(dy), adz = fabsf(dz);
            hsum += (adx < 1.f) ? 0.5f * dx * dx : adx - 0.5f;
            hsum += (ady < 1.f) ? 0.5f * dy * dy : ady - 0.5f;
            hsum += (adz < 1.f) ? 0.5f * dz * dz : adz - 0.5f;
        }
    }

    // scalar tail (only if B is odd)
    for (int i = (nchunks << 1) + blockIdx.x * blockDim.x + threadIdx.x; i < B;
         i += stride) {
        float qx = quat[(size_t)i * 4 + 0], qy = quat[(size_t)i * 4 + 1];
        float qz = quat[(size_t)i * 4 + 2], qw = quat[(size_t)i * 4 + 3];
        float bx = bias[(size_t)i * 3 + 0], by = bias[(size_t)i * 3 + 1],
              bz = bias[(size_t)i * 3 + 2];
        const float* xb = batchX + (size_t)i * SF + last_off;
        float ax = xb[0] - bx, ay = xb[1] - by, az = xb[2] - bz;
        int ix = indices[i] - (S - 1);
        if (ix < 0) ix = 0;
        const float* pp = pos_all + (size_t)ix * 3;
        const float* vp = vel_all + (size_t)ix * 3;

        float t0 = -(qy * ax + qz * ay + qw * az);
        float t1 =   qx * ax + qz * az - qw * ay;
        float t2 =   qx * ay - qy * az + qw * ax;
        float t3 =   qx * az + qy * ay - qz * ax;
        float rx = -t0 * qy + t1 * qx - t2 * qw + t3 * qz;
        float ry = -t0 * qz + t1 * qw + t2 * qx - t3 * qy;
        float rz = -t0 * qw - t1 * qz + t2 * qy + t3 * qx;

        float px = pp[0] + vp[0] * DT + half_dt2 * gx + half_dt2 * rx;
        float py = pp[1] + vp[1] * DT + half_dt2 * gy + half_dt2 * ry;
        float pz = pp[2] + vp[2] * DT + half_dt2 * gz + half_dt2 * rz;

        float dx = px - tpos[(size_t)i * 3 + 0];
        float dy = py - tpos[(size_t)i * 3 + 1];
        float dz = pz - tpos[(size_t)i * 3 + 2];

        float adx = fabsf(dx), ady = fabsf(dy), adz = fabsf(dz);
        hsum += (adx < 1.f) ? 0.5f * dx * dx : adx - 0.5f;
        hsum += (ady < 1.f) ? 0.5f * dy * dy : ady - 0.5f;
        hsum += (adz < 1.f) ? 0.5f * dz * dz : adz - 0.5f;
    }

    // ---- block reduction ----
    for (int off = 32; off > 0; off >>= 1)
        hsum += __shfl_down(hsum, off);

    __shared__ float wsum[NTHREADS / 64];
    __shared__ bool amLast;
    int lane = threadIdx.x & 63;
    int wid  = threadIdx.x >> 6;
    if (lane == 0) wsum[wid] = hsum;
    __syncthreads();

    if (threadIdx.x == 0) {
        float s = 0.f;
        for (int w = 0; w < NTHREADS / 64; ++w) s += wsum[w];
        __hip_atomic_store(&partials[blockIdx.x], s,
                           __ATOMIC_RELEASE, __HIP_MEMORY_SCOPE_AGENT);
        unsigned prev = __hip_atomic_fetch_add(counter, 1u,
                           __ATOMIC_ACQ_REL, __HIP_MEMORY_SCOPE_AGENT);
        amLast = (prev == (unsigned)(nblocks - 1));
    }
    __syncthreads();

    // ---- last block: final deterministic reduction ----
    if (amLast) {
        float t = 0.f;
        for (int i = threadIdx.x; i < nblocks; i += NTHREADS)
            t += __hip_atomic_load(&partials[i],
                                   __ATOMIC_RELAXED, __HIP_MEMORY_SCOPE_AGENT);
        for (int off = 32; off > 0; off >>= 1)
            t += __shfl_down(t, off);
        __syncthreads();          // wsum reuse
        if (lane == 0) wsum[wid] = t;
        __syncthreads();
        if (threadIdx.x == 0) {
            float tot = 0.f;
            for (int w = 0; w < NTHREADS / 64; ++w) tot += wsum[w];
            out[0] = tot * inv_cnt;
            __hip_atomic_store(counter, 0u,
                               __ATOMIC_RELAXED, __HIP_MEMORY_SCOPE_AGENT);
        }
    }
}

extern "C" void kernel_launch(void* const* d_in, const int* in_sizes, int n_in,
                              void* d_out, int out_size, void* d_ws, size_t ws_size,
                              hipStream_t stream) {
    const float* quat    = (const float*)d_in[0];
    const float* tpos    = (const float*)d_in[1];
    const float* bias    = (const float*)d_in[2];
    const float* batchX  = (const float*)d_in[3];
    const float* pos_all = (const float*)d_in[4];
    const float* vel_all = (const float*)d_in[5];
    const float* grav    = (const float*)d_in[6];
    const int*   indices = (const int*)d_in[7];
    const int*   seqlen  = (const int*)d_in[8];

    const int B  = in_sizes[0] / 4;
    const int SF = in_sizes[3] / B;

    unsigned* counter = (unsigned*)d_ws;
    float* partials = (float*)((char*)d_ws + 64);

    const int nchunks = B >> 1;
    int nblocks = (nchunks + NTHREADS - 1) / NTHREADS;   // 2048 for B=1M
    if (nblocks < 1) nblocks = 1;

    float inv_cnt = (float)(1.0 / (3.0 * (double)B));

    hipMemsetAsync(counter, 0, sizeof(unsigned), stream);

    pos_loss_fused<<<nblocks, NTHREADS, 0, stream>>>(
        quat, tpos, bias, batchX, pos_all, vel_all, grav, indices, seqlen,
        B, SF, partials, counter, inv_cnt, (float*)d_out, nblocks);
}

// Round 5
// 72.808 us; speedup vs baseline: 2.8487x; 2.8487x over previous
//
#include <hip/hip_runtime.h>
#include <math.h>

#define DT 0.005f
#define NBLOCKS 2048
#define NTHREADS 256

typedef float fvec4 __attribute__((ext_vector_type(4)));

__device__ __forceinline__ fvec4 ntload4f(const float* p) {
    return __builtin_nontemporal_load(reinterpret_cast<const fvec4*>(p));
}
__device__ __forceinline__ float ntloadf(const float* p) {
    return __builtin_nontemporal_load(p);
}
__device__ __forceinline__ int ntloadi(const int* p) {
    return __builtin_nontemporal_load(p);
}

__global__ __launch_bounds__(NTHREADS) void pos_loss_partial(
    const float* __restrict__ quat,     // B*4
    const float* __restrict__ tpos,     // B*3
    const float* __restrict__ bias,     // B*3
    const float* __restrict__ batchX,   // B*S*F
    const float* __restrict__ pos_all,  // N*3
    const float* __restrict__ vel_all,  // N*3
    const float* __restrict__ grav,     // 3
    const int*   __restrict__ indices,  // B
    const int*   __restrict__ seq_len_p,// 1
    int B, int SF,
    float* __restrict__ partials)       // NBLOCKS
{
    const int S = *seq_len_p;
    const int F = SF / S;
    const int last_off = (S - 1) * F;
    const float gx = grav[0], gy = grav[1], gz = grav[2];
    const float half_dt2 = 0.5f * DT * DT;

    float hsum = 0.f;

    for (int i = blockIdx.x * blockDim.x + threadIdx.x; i < B;
         i += gridDim.x * blockDim.x) {

        // ---- index + gathers first (longest dependency chain; cacheable) ----
        int idx = ntloadi(indices + i) - (S - 1);
        if (idx < 0) idx = 0;
        const float* pp = pos_all + (size_t)idx * 3;
        const float* vp = vel_all + (size_t)idx * 3;
        float p0x = pp[0], p0y = pp[1], p0z = pp[2];
        float v0x = vp[0], v0y = vp[1], v0z = vp[2];

        // ---- streaming loads: nontemporal (no reuse, keep L3 for gathers) ----
        fvec4 q = ntload4f(quat + (size_t)i * 4);

        const float* tp = tpos + (size_t)i * 3;
        float tpx = ntloadf(tp + 0), tpy = ntloadf(tp + 1), tpz = ntloadf(tp + 2);

        const float* bp = bias + (size_t)i * 3;
        float bx = ntloadf(bp + 0), by = ntloadf(bp + 1), bz = ntloadf(bp + 2);

        const float* xb = batchX + (size_t)i * SF + last_off;
        float ax = ntloadf(xb + 0) - bx;
        float ay = ntloadf(xb + 1) - by;
        float az = ntloadf(xb + 2) - bz;

        // ---- quat_rotate(q, a): t = q * (0, a) ----
        float t0 = -(q.y * ax + q.z * ay + q.w * az);
        float t1 =   q.x * ax + q.z * az - q.w * ay;
        float t2 =   q.x * ay - q.y * az + q.w * ax;
        float t3 =   q.x * az + q.y * ay - q.z * ax;
        // (t * q_conj) vector part
        float rx = -t0 * q.y + t1 * q.x - t2 * q.w + t3 * q.z;
        float ry = -t0 * q.z + t1 * q.w + t2 * q.x - t3 * q.y;
        float rz = -t0 * q.w - t1 * q.z + t2 * q.y + t3 * q.x;

        // pred = p0 + v0*DT + 0.5*g*DT^2 + 0.5*rot*DT^2
        float px = p0x + v0x * DT + half_dt2 * gx + half_dt2 * rx;
        float py = p0y + v0y * DT + half_dt2 * gy + half_dt2 * ry;
        float pz = p0z + v0z * DT + half_dt2 * gz + half_dt2 * rz;

        float dx = px - tpx, dy = py - tpy, dz = pz - tpz;

        float adx = fabsf(dx), ady = fabsf(dy), adz = fabsf(dz);
        hsum += (adx < 1.f) ? 0.5f * dx * dx : adx - 0.5f;
        hsum += (ady < 1.f) ? 0.5f * dy * dy : ady - 0.5f;
        hsum += (adz < 1.f) ? 0.5f * dz * dz : adz - 0.5f;
    }

    // wave-64 reduce
    for (int off = 32; off > 0; off >>= 1)
        hsum += __shfl_down(hsum, off);

    __shared__ float wsum[NTHREADS / 64];
    int lane = threadIdx.x & 63;
    int wid  = threadIdx.x >> 6;
    if (lane == 0) wsum[wid] = hsum;
    __syncthreads();

    if (threadIdx.x == 0) {
        float s = 0.f;
        for (int w = 0; w < NTHREADS / 64; ++w) s += wsum[w];
        partials[blockIdx.x] = s;
    }
}

__global__ __launch_bounds__(NTHREADS) void pos_loss_finish(
    const float* __restrict__ partials, int nb, float inv_cnt,
    float* __restrict__ out)
{
    float s = 0.f;
    for (int i = threadIdx.x; i < nb; i += NTHREADS) s += partials[i];

    for (int off = 32; off > 0; off >>= 1)
        s += __shfl_down(s, off);

    __shared__ float wsum[NTHREADS / 64];
    int lane = threadIdx.x & 63;
    int wid  = threadIdx.x >> 6;
    if (lane == 0) wsum[wid] = s;
    __syncthreads();

    if (threadIdx.x == 0) {
        float tot = 0.f;
        for (int w = 0; w < NTHREADS / 64; ++w) tot += wsum[w];
        out[0] = tot * inv_cnt;
    }
}

extern "C" void kernel_launch(void* const* d_in, const int* in_sizes, int n_in,
                              void* d_out, int out_size, void* d_ws, size_t ws_size,
                              hipStream_t stream) {
    const float* quat    = (const float*)d_in[0];
    const float* tpos    = (const float*)d_in[1];
    const float* bias    = (const float*)d_in[2];
    const float* batchX  = (const float*)d_in[3];
    const float* pos_all = (const float*)d_in[4];
    const float* vel_all = (const float*)d_in[5];
    const float* grav    = (const float*)d_in[6];
    const int*   indices = (const int*)d_in[7];
    const int*   seqlen  = (const int*)d_in[8];

    const int B  = in_sizes[0] / 4;
    const int SF = in_sizes[3] / B;

    float* partials = (float*)d_ws;
    float inv_cnt = (float)(1.0 / (3.0 * (double)B));

    pos_loss_partial<<<NBLOCKS, NTHREADS, 0, stream>>>(
        quat, tpos, bias, batchX, pos_all, vel_all, grav, indices, seqlen,
        B, SF, partials);

    pos_loss_finish<<<1, NTHREADS, 0, stream>>>(
        partials, NBLOCKS, inv_cnt, (float*)d_out);
}